// Round 11
// baseline (178.402 us; speedup 1.0000x reference)
//
#include <hip/hip_runtime.h>
#include <math.h>

// Shapes (fixed by the problem)
#define Hn 8
#define Sn 1024
#define Dn 64
#define KG 10

// Bias tables: dist in [0,10), energy in [0,5)
#define TN 2048
#define RD 10.25f
#define RE 5.125f

// k-split: grid (Sn/64, Hn, KS) = 1024 blocks; 48 KB LDS -> 3 blocks/CU
#define KS 8

typedef __attribute__((ext_vector_type(8))) short bf16x8;
typedef __attribute__((ext_vector_type(4))) float f32x4;
typedef unsigned short u16;
typedef unsigned int u32;

__device__ inline float bf2f(u16 u) {
    union { u32 i; float f; } v;
    v.i = ((u32)u) << 16;
    return v.f;
}

__device__ inline u16 f2bf(float f) {
    union { float f; u32 i; } v;
    v.f = f;
    u32 i = v.i;
    return (u16)((i + 0x7FFFu + ((i >> 16) & 1u)) >> 16);   // RNE
}

// Fire-and-forget global->LDS DMA, 16 B per lane (R7/R8-proven mechanism).
__device__ inline void stage16(const void* g, void* l) {
    __builtin_amdgcn_global_load_lds(
        (const __attribute__((address_space(1))) unsigned int*)g,
        (__attribute__((address_space(3))) unsigned int*)l,
        16, 0, 0);
}

// ---------------------------------------------------------------------------
// RBF (10 gaussians) -> 10x10 MLP (exact gelu) -> scalar, all f32.
// ---------------------------------------------------------------------------
__device__ float bias_eval(float x,
                           const float* __restrict__ mu, const float* __restrict__ sg,
                           const float* __restrict__ bb,
                           const float* __restrict__ W1, const float* __restrict__ b1,
                           const float* __restrict__ W2, const float* __restrict__ b2) {
    const float inv_s2pi = 0.39894228040143267794f;
    float psi[KG];
#pragma unroll
    for (int k = 0; k < KG; k++) {
        float s = sg[k];
        float z = (x + bb[k] - mu[k]) / s;
        psi[k] = __expf(-0.5f * z * z) * (inv_s2pi / s);
    }
    float out = b2[0];
#pragma unroll
    for (int l = 0; l < KG; l++) {
        float a = b1[l];
#pragma unroll
        for (int k = 0; k < KG; k++) a += psi[k] * W1[l * KG + k];
        float g = 0.5f * a * (1.0f + erff(a * 0.70710678118654752440f));
        out += g * W2[l];
    }
    return out;
}

// ---------------------------------------------------------------------------
// Fused prepass (unchanged).
// ---------------------------------------------------------------------------
#define QK4 262144              // (2*Hn*Sn*Dn)/4
#define VTN 524288              // Hn*Sn*Dn

__global__ __launch_bounds__(256) void prep_kernel(
    const float* __restrict__ Q, const float* __restrict__ K, const float* __restrict__ V,
    const float* __restrict__ muD, const float* __restrict__ sgD, const float* __restrict__ bD,
    const float* __restrict__ muE, const float* __restrict__ sgE, const float* __restrict__ bE,
    const float* __restrict__ W1, const float* __restrict__ b1,
    const float* __restrict__ W2, const float* __restrict__ b2,
    u32* __restrict__ tab, u16* __restrict__ Qb, u16* __restrict__ Kb, u16* __restrict__ VTi)
{
    int id = blockIdx.x * 256 + threadIdx.x;
    if (id < 2 * TN) {
        int which = (id >= TN);
        int idx = id & (TN - 1);
        float h = (which ? RE : RD) / (float)TN;
        float x0 = idx * h;
        float v0, v1;
        if (which) {
            v0 = bias_eval(x0,     muE, sgE, bE, W1, b1, W2, b2);
            v1 = bias_eval(x0 + h, muE, sgE, bE, W1, b1, W2, b2);
        } else {
            v0 = bias_eval(x0,     muD, sgD, bD, W1, b1, W2, b2);
            v1 = bias_eval(x0 + h, muD, sgD, bD, W1, b1, W2, b2);
        }
        tab[id] = (u32)f2bf(v0) | ((u32)f2bf(v1 - v0) << 16);
    } else if (id < 2 * TN + QK4) {
        int i = id - 2 * TN;
        int arr = i >> 17;          // 0 = Q, 1 = K
        i &= (1 << 17) - 1;
        float4 v = ((const float4*)(arr ? K : Q))[i];
        ushort4 o;
        o.x = f2bf(v.x); o.y = f2bf(v.y); o.z = f2bf(v.z); o.w = f2bf(v.w);
        ((ushort4*)(arr ? Kb : Qb))[i] = o;
    } else if (id < 2 * TN + QK4 + VTN) {
        int g = id - (2 * TN + QK4);
        int h = g >> 16;
        int d = (g >> 10) & 63;
        int s = g & 1023;
        int t = s >> 5, q = (s >> 3) & 3, j = s & 7;
        int src_s = (t << 5) + (q << 2) + (j & 3) + ((j >> 2) << 4);
        VTi[g] = f2bf(V[(((size_t)h << 10) + src_s) * Dn + d]);
    }
}

__device__ inline float lerp_tab(const u32* __restrict__ st, float x, float invh) {
    float tf = x * invh;
    int i = (int)tf;
    i = max(0, min(i, TN - 1));
    float fr = tf - (float)i;
    u32 p = st[i];
    return fmaf(bf2f((u16)(p >> 16)), fr, bf2f((u16)p));
}

// ---------------------------------------------------------------------------
// Fused flash attention, shared K/V staging, SINGLE 32 KB tile buffer.
// R10 lesson: 80 KB LDS (double buffer) filled the pool exactly -> ~1.5
// blocks/CU resident, cancelling the traffic win. Here: LDS = 16 KB table +
// 32 KB buffer = 48 KB -> 3 blocks/CU; KS=8 -> 1024 blocks so the capacity
// is usable. Per tile: STAGE -> barrier (drain DMA + share) -> compute ->
// barrier (reads done before overwrite). Each block covers 64 q x 128 k
// (4 tiles); per-wave partial (m,l,U); combine merges KS=8 per q-row.
// Traffic: 96 MB D/E/M + 32 MB K/V + 34 MB partials vs R8's 229 MB, at
// 12 waves/CU vs R8's 8.
// ---------------------------------------------------------------------------
#define BUFSZ 32768

__global__ __launch_bounds__(256) void attn_kernel(
    const u16* __restrict__ Qb, const u16* __restrict__ Kb, const u16* __restrict__ VTi,
    const float* __restrict__ Dm, const float* __restrict__ Em, const int* __restrict__ Mk,
    const u32* __restrict__ gtab,
    float* __restrict__ Up, float* __restrict__ Mp, float* __restrict__ Lp)
{
    __shared__ __align__(16) u32 sTab[2 * TN];      // 16 KB
    __shared__ __align__(16) char sBuf[BUFSZ];      // 32 KB single tile buffer

    const int tid = threadIdx.x;
    {   // stage tables: 1024 uint4 over 256 threads
        const uint4* g4 = (const uint4*)gtab;
        uint4* s4 = (uint4*)sTab;
#pragma unroll
        for (int i = 0; i < 4; i++) s4[tid + 256 * i] = g4[tid + 256 * i];
    }

    const int h    = blockIdx.y;
    const int qb   = blockIdx.x;        // 64-row q-panel (0..15)
    const int ks   = blockIdx.z;        // k-range [ks*128, ks*128+128)
    const int wave = tid >> 6;
    const int lane = tid & 63;
    const int quad = lane >> 4;
    const int l16  = lane & 15;
    const int q0   = qb * 64 + wave * 16;   // this wave's q-tile
    const int kbase = ks * 128;

    const u16* Qh = Qb  + (size_t)h * Sn * Dn;
    const u16* Kh = Kb  + (size_t)h * Sn * Dn;
    const u16* Vh = VTi + (size_t)h * Dn * Sn;
    const float* Dh = Dm + (size_t)h * Sn * Sn + (size_t)(q0 + l16) * Sn;
    const float* Eh = Em + (size_t)h * Sn * Sn + (size_t)(q0 + l16) * Sn;
    const int*   Mh = Mk + (size_t)h * Sn * Sn + (size_t)(q0 + l16) * Sn;
    const float invhD = (float)TN / RD;
    const float invhE = (float)TN / RE;
    const float scale = 0.08838834764831845f;       // 1/sqrt(2*64)

    // Persistent Q B-fragments for this wave's q-tile
    const bf16x8 bQ0 = *(const bf16x8*)(Qh + (q0 + l16) * Dn + quad * 8);
    const bf16x8 bQ1 = *(const bf16x8*)(Qh + (q0 + l16) * Dn + 32 + quad * 8);

    // Tile buffer layout (32 KB):
    //  [0,4K)   K chunks 0-3 (staged by waves 0-1)
    //  [4K,8K)  V chunks 0-3 (staged by waves 2-3)
    //  [8K,32K) D/E/M: wave w region at 8K + w*6K (6 chunks of 1 KB)
#define STAGE(tt) do {                                                         \
        const int k0_ = kbase + (tt) * 32;                                     \
        char* b_ = sBuf;                                                       \
        if (wave < 2) {                                                        \
            const u16* kr_ = Kh + (size_t)(k0_ + l16 + wave * 16) * Dn + quad * 8; \
            stage16(kr_,      b_ + wave * 2048);                               \
            stage16(kr_ + 32, b_ + wave * 2048 + 1024);                        \
        } else {                                                               \
            const int c_ = (wave - 2) * 2;                                     \
            const u16* vr_ = Vh + k0_ + quad * 8 + (size_t)(l16 + 16 * c_) * Sn; \
            stage16(vr_,           b_ + 4096 + c_ * 1024);                     \
            stage16(vr_ + 16 * Sn, b_ + 4096 + c_ * 1024 + 1024);              \
        }                                                                      \
        const float* dr_ = Dh + k0_ + quad * 4;                                \
        const float* er_ = Eh + k0_ + quad * 4;                                \
        const int*   mr_ = Mh + k0_ + quad * 4;                                \
        char* w_ = b_ + 8192 + wave * 6144;                                    \
        stage16(dr_,       w_);                                                \
        stage16(dr_ + 16,  w_ + 1024);                                         \
        stage16(er_,       w_ + 2048);                                         \
        stage16(er_ + 16,  w_ + 3072);                                         \
        stage16(mr_,       w_ + 4096);                                         \
        stage16(mr_ + 16,  w_ + 5120);                                         \
    } while (0)

    f32x4 O0 = {0.f, 0.f, 0.f, 0.f}, O1 = O0, O2 = O0, O3 = O0;
    float m_run = -1e30f, l_run = 0.f;

    for (int t = 0; t < 4; t++) {
        STAGE(t);
        // barrier 1: each wave's vmcnt(0) drains its DMAs, then all waves
        // see the shared K/V + the table (first iteration)
        __syncthreads();

        const char* ls = sBuf + lane * 16;
        const bf16x8 aK00 = *(const bf16x8*)(ls);
        const bf16x8 aK01 = *(const bf16x8*)(ls + 1024);
        const bf16x8 aK10 = *(const bf16x8*)(ls + 2048);
        const bf16x8 aK11 = *(const bf16x8*)(ls + 3072);
        const bf16x8 bV0  = *(const bf16x8*)(ls + 4096);
        const bf16x8 bV1  = *(const bf16x8*)(ls + 5120);
        const bf16x8 bV2  = *(const bf16x8*)(ls + 6144);
        const bf16x8 bV3  = *(const bf16x8*)(ls + 7168);
        const char* ld = sBuf + 8192 + wave * 6144 + lane * 16;
        const float4 Dv0  = *(const float4*)(ld);
        const float4 Dv1  = *(const float4*)(ld + 1024);
        const float4 Ev0  = *(const float4*)(ld + 2048);
        const float4 Ev1  = *(const float4*)(ld + 3072);
        const int4   Mv0  = *(const int4*)(ld + 4096);
        const int4   Mv1  = *(const int4*)(ld + 5120);

        f32x4 s0 = {0.f, 0.f, 0.f, 0.f}, s1 = s0;
        s0 = __builtin_amdgcn_mfma_f32_16x16x32_bf16(aK00, bQ0, s0, 0, 0, 0);
        s0 = __builtin_amdgcn_mfma_f32_16x16x32_bf16(aK01, bQ1, s0, 0, 0, 0);
        s1 = __builtin_amdgcn_mfma_f32_16x16x32_bf16(aK10, bQ0, s1, 0, 0, 0);
        s1 = __builtin_amdgcn_mfma_f32_16x16x32_bf16(aK11, bQ1, s1, 0, 0, 0);

        const float dv0[4] = {Dv0.x, Dv0.y, Dv0.z, Dv0.w};
        const float dv1[4] = {Dv1.x, Dv1.y, Dv1.z, Dv1.w};
        const float ev0[4] = {Ev0.x, Ev0.y, Ev0.z, Ev0.w};
        const float ev1[4] = {Ev1.x, Ev1.y, Ev1.z, Ev1.w};
        const int   mv0[4] = {Mv0.x, Mv0.y, Mv0.z, Mv0.w};
        const int   mv1[4] = {Mv1.x, Mv1.y, Mv1.z, Mv1.w};

        float sc0[4], sc1[4];
#pragma unroll
        for (int r = 0; r < 4; r++) {
            float v0 = s0[r] * scale + lerp_tab(sTab, dv0[r], invhD)
                                     + lerp_tab(sTab + TN, ev0[r], invhE);
            v0 = fminf(fmaxf(v0, -80.f), 80.f);
            sc0[r] = (mv0[r] == 0) ? -1e9f : v0;
            float v1 = s1[r] * scale + lerp_tab(sTab, dv1[r], invhD)
                                     + lerp_tab(sTab + TN, ev1[r], invhE);
            v1 = fminf(fmaxf(v1, -80.f), 80.f);
            sc1[r] = (mv1[r] == 0) ? -1e9f : v1;
        }

        // row max: local over 8 values, then across quads (2 shuffles)
        float mloc = fmaxf(fmaxf(fmaxf(sc0[0], sc0[1]), fmaxf(sc0[2], sc0[3])),
                           fmaxf(fmaxf(sc1[0], sc1[1]), fmaxf(sc1[2], sc1[3])));
        mloc = fmaxf(mloc, __shfl_xor(mloc, 16, 64));
        mloc = fmaxf(mloc, __shfl_xor(mloc, 32, 64));

        const float mn = fmaxf(m_run, mloc);
        const float al = __expf(m_run - mn);
        m_run = mn;

        float p0[4], p1[4], ll = 0.f;
#pragma unroll
        for (int r = 0; r < 4; r++) {
            p0[r] = __expf(sc0[r] - mn);
            p1[r] = __expf(sc1[r] - mn);
            ll += p0[r] + p1[r];
        }
        ll += __shfl_xor(ll, 16, 64);
        ll += __shfl_xor(ll, 32, 64);
        l_run = l_run * al + ll;

        // P A-fragment straight from registers (k-order matches permuted V)
        bf16x8 aP;
#pragma unroll
        for (int r = 0; r < 4; r++) {
            aP[r]     = (short)f2bf(p0[r]);
            aP[4 + r] = (short)f2bf(p1[r]);
        }

        // O rescale: alpha for row quad*4+r lives in lane (quad*4+r)
        const float a0 = __shfl(al, quad * 4 + 0, 64);
        const float a1 = __shfl(al, quad * 4 + 1, 64);
        const float a2 = __shfl(al, quad * 4 + 2, 64);
        const float a3 = __shfl(al, quad * 4 + 3, 64);
        O0[0] *= a0; O0[1] *= a1; O0[2] *= a2; O0[3] *= a3;
        O1[0] *= a0; O1[1] *= a1; O1[2] *= a2; O1[3] *= a3;
        O2[0] *= a0; O2[1] *= a1; O2[2] *= a2; O2[3] *= a3;
        O3[0] *= a0; O3[1] *= a1; O3[2] *= a2; O3[3] *= a3;

        O0 = __builtin_amdgcn_mfma_f32_16x16x32_bf16(aP, bV0, O0, 0, 0, 0);
        O1 = __builtin_amdgcn_mfma_f32_16x16x32_bf16(aP, bV1, O1, 0, 0, 0);
        O2 = __builtin_amdgcn_mfma_f32_16x16x32_bf16(aP, bV2, O2, 0, 0, 0);
        O3 = __builtin_amdgcn_mfma_f32_16x16x32_bf16(aP, bV3, O3, 0, 0, 0);

        // barrier 2: all waves' LDS reads complete before next STAGE
        __syncthreads();
    }
#undef STAGE

    // Per-wave partial (m, l, U) straight to workspace.
    const int pb = (h * 64 + qb * 4 + wave) * KS + ks;
    float* up = Up + (size_t)pb * 1024;
#pragma unroll
    for (int r = 0; r < 4; r++) {
        const int row = quad * 4 + r;
        up[row * 64 +  0 + l16] = O0[r];
        up[row * 64 + 16 + l16] = O1[r];
        up[row * 64 + 32 + l16] = O2[r];
        up[row * 64 + 48 + l16] = O3[r];
    }
    if (lane < 16) {
        Mp[pb * 16 + lane] = m_run;
        Lp[pb * 16 + lane] = l_run;
    }
}

// ---------------------------------------------------------------------------
// Merge the KS=8 partials per q-row.
// ---------------------------------------------------------------------------
__global__ __launch_bounds__(256) void combine_kernel(
    const float* __restrict__ Up, const float* __restrict__ Mp,
    const float* __restrict__ Lp, float* __restrict__ out)
{
    const int g  = blockIdx.x * 256 + threadIdx.x;
    const int r  = g >> 4;                 // global row 0..8191
    const int c4 = (g & 15) * 4;
    const int h  = r >> 10;
    const int s  = r & 1023;
    const int qt = s >> 4;                 // q-tile 0..63
    const int r16 = s & 15;
    const int pb0 = (h * 64 + qt) * KS;

    float m[KS], l[KS];
#pragma unroll
    for (int k = 0; k < KS; k++) {
        m[k] = Mp[(pb0 + k) * 16 + r16];
        l[k] = Lp[(pb0 + k) * 16 + r16];
    }
    float M = m[0];
#pragma unroll
    for (int k = 1; k < KS; k++) M = fmaxf(M, m[k]);
    float f[KS], L = 0.f;
#pragma unroll
    for (int k = 0; k < KS; k++) {
        f[k] = __expf(m[k] - M);
        L += l[k] * f[k];
    }
    const float inv = 1.0f / L;

    float acc[4] = {0.f, 0.f, 0.f, 0.f};
#pragma unroll
    for (int k = 0; k < KS; k++) {
        const float4 u = *(const float4*)(Up + (size_t)(pb0 + k) * 1024 + r16 * 64 + c4);
        acc[0] += u.x * f[k]; acc[1] += u.y * f[k];
        acc[2] += u.z * f[k]; acc[3] += u.w * f[k];
    }
    float4 ov = {acc[0] * inv, acc[1] * inv, acc[2] * inv, acc[3] * inv};
    *(float4*)(out + (size_t)r * Dn + c4) = ov;
}

// ---------------------------------------------------------------------------
extern "C" void kernel_launch(void* const* d_in, const int* in_sizes, int n_in,
                              void* d_out, int out_size, void* d_ws, size_t ws_size,
                              hipStream_t stream) {
    const float* Q    = (const float*)d_in[0];
    const float* K    = (const float*)d_in[1];
    const float* V    = (const float*)d_in[2];
    const float* Dm   = (const float*)d_in[3];
    const float* Em   = (const float*)d_in[4];
    const int*   Mask = (const int*)d_in[5];
    const float* muD  = (const float*)d_in[6];
    const float* sgD  = (const float*)d_in[7];
    const float* bD   = (const float*)d_in[8];
    const float* muE  = (const float*)d_in[9];
    const float* sgE  = (const float*)d_in[10];
    const float* bE   = (const float*)d_in[11];
    const float* W1   = (const float*)d_in[12];
    const float* b1   = (const float*)d_in[13];
    const float* W2   = (const float*)d_in[14];
    const float* b2   = (const float*)d_in[15];

    // ws: tab 16KB | Qb/Kb/VTi 1MB each | Up 16.8MB | Mp,Lp 256KB each (~20.4 MB)
    u32* tab = (u32*)d_ws;
    u16* Qb  = (u16*)((char*)d_ws + 2 * TN * 4);
    u16* Kb  = Qb + (size_t)Hn * Sn * Dn;
    u16* VTi = Kb + (size_t)Hn * Sn * Dn;
    float* Up = (float*)(VTi + (size_t)Hn * Sn * Dn);
    float* Mp = Up + (size_t)Hn * 64 * KS * 16 * 64;
    float* Lp = Mp + (size_t)Hn * 64 * KS * 16;

    const int prep_threads = 2 * TN + QK4 + VTN;           // 790528
    prep_kernel<<<prep_threads / 256, 256, 0, stream>>>(
        Q, K, V, muD, sgD, bD, muE, sgE, bE, W1, b1, W2, b2,
        tab, Qb, Kb, VTi);

    dim3 grid(Sn / 64, Hn, KS);
    attn_kernel<<<grid, 256, 0, stream>>>(Qb, Kb, VTi, Dm, Em, Mask, tab,
                                          Up, Mp, Lp);

    combine_kernel<<<(Hn * Sn * 16) / 256, 256, 0, stream>>>(Up, Mp, Lp,
                                                             (float*)d_out);
}

// Round 12
// 175.336 us; speedup vs baseline: 1.0175x; 1.0175x over previous
//
#include <hip/hip_runtime.h>
#include <math.h>

// Shapes (fixed by the problem)
#define Hn 8
#define Sn 1024
#define Dn 64
#define KG 10

// Bias tables: dist in [0,10), energy in [0,5)
#define TN 2048
#define RD 10.25f
#define RE 5.125f

typedef __attribute__((ext_vector_type(8))) short bf16x8;
typedef __attribute__((ext_vector_type(4))) float f32x4;
typedef unsigned short u16;
typedef unsigned int u32;

__device__ inline float bf2f(u16 u) {
    union { u32 i; float f; } v;
    v.i = ((u32)u) << 16;
    return v.f;
}

__device__ inline u16 f2bf(float f) {
    union { float f; u32 i; } v;
    v.f = f;
    u32 i = v.i;
    return (u16)((i + 0x7FFFu + ((i >> 16) & 1u)) >> 16);   // RNE
}

// Fire-and-forget global->LDS DMA, 16 B per lane (R7/R8-proven mechanism:
// no VGPR destination -> RA cannot re-serialize). Readback at lane*16 is
// the identity.
__device__ inline void stage16(const void* g, void* l) {
    __builtin_amdgcn_global_load_lds(
        (const __attribute__((address_space(1))) unsigned int*)g,
        (__attribute__((address_space(3))) unsigned int*)l,
        16, 0, 0);
}

// ---------------------------------------------------------------------------
// RBF (10 gaussians) -> 10x10 MLP (exact gelu) -> scalar, all f32.
// ---------------------------------------------------------------------------
__device__ float bias_eval(float x,
                           const float* __restrict__ mu, const float* __restrict__ sg,
                           const float* __restrict__ bb,
                           const float* __restrict__ W1, const float* __restrict__ b1,
                           const float* __restrict__ W2, const float* __restrict__ b2) {
    const float inv_s2pi = 0.39894228040143267794f;
    float psi[KG];
#pragma unroll
    for (int k = 0; k < KG; k++) {
        float s = sg[k];
        float z = (x + bb[k] - mu[k]) / s;
        psi[k] = __expf(-0.5f * z * z) * (inv_s2pi / s);
    }
    float out = b2[0];
#pragma unroll
    for (int l = 0; l < KG; l++) {
        float a = b1[l];
#pragma unroll
        for (int k = 0; k < KG; k++) a += psi[k] * W1[l * KG + k];
        float g = 0.5f * a * (1.0f + erff(a * 0.70710678118654752440f));
        out += g * W2[l];
    }
    return out;
}

// ---------------------------------------------------------------------------
// Fused prepass (unchanged).
// ---------------------------------------------------------------------------
#define QK4 262144              // (2*Hn*Sn*Dn)/4
#define VTN 524288              // Hn*Sn*Dn

__global__ __launch_bounds__(256) void prep_kernel(
    const float* __restrict__ Q, const float* __restrict__ K, const float* __restrict__ V,
    const float* __restrict__ muD, const float* __restrict__ sgD, const float* __restrict__ bD,
    const float* __restrict__ muE, const float* __restrict__ sgE, const float* __restrict__ bE,
    const float* __restrict__ W1, const float* __restrict__ b1,
    const float* __restrict__ W2, const float* __restrict__ b2,
    u32* __restrict__ tab, u16* __restrict__ Qb, u16* __restrict__ Kb, u16* __restrict__ VTi)
{
    int id = blockIdx.x * 256 + threadIdx.x;
    if (id < 2 * TN) {
        int which = (id >= TN);
        int idx = id & (TN - 1);
        float h = (which ? RE : RD) / (float)TN;
        float x0 = idx * h;
        float v0, v1;
        if (which) {
            v0 = bias_eval(x0,     muE, sgE, bE, W1, b1, W2, b2);
            v1 = bias_eval(x0 + h, muE, sgE, bE, W1, b1, W2, b2);
        } else {
            v0 = bias_eval(x0,     muD, sgD, bD, W1, b1, W2, b2);
            v1 = bias_eval(x0 + h, muD, sgD, bD, W1, b1, W2, b2);
        }
        tab[id] = (u32)f2bf(v0) | ((u32)f2bf(v1 - v0) << 16);
    } else if (id < 2 * TN + QK4) {
        int i = id - 2 * TN;
        int arr = i >> 17;          // 0 = Q, 1 = K
        i &= (1 << 17) - 1;
        float4 v = ((const float4*)(arr ? K : Q))[i];
        ushort4 o;
        o.x = f2bf(v.x); o.y = f2bf(v.y); o.z = f2bf(v.z); o.w = f2bf(v.w);
        ((ushort4*)(arr ? Kb : Qb))[i] = o;
    } else if (id < 2 * TN + QK4 + VTN) {
        int g = id - (2 * TN + QK4);
        int h = g >> 16;
        int d = (g >> 10) & 63;
        int s = g & 1023;
        int t = s >> 5, q = (s >> 3) & 3, j = s & 7;
        int src_s = (t << 5) + (q << 2) + (j & 3) + ((j >> 2) << 4);
        VTi[g] = f2bf(V[(((size_t)h << 10) + src_s) * Dn + d]);
    }
}

__device__ inline float lerp_tab(const u32* __restrict__ st, float x, float invh) {
    float tf = x * invh;
    int i = (int)tf;
    i = max(0, min(i, TN - 1));
    float fr = tf - (float)i;
    u32 p = st[i];
    return fmaf(bf2f((u16)(p >> 16)), fr, bf2f((u16)p));
}

// ---------------------------------------------------------------------------
// Fused flash attention: R8's barrier-free private-staging pipeline (the
// only structure that ran the VMEM pipe at ~5.3 TB/s) with 0.71x traffic:
//  - 512-thread blocks; the 8 waves share ONE 32-row q-panel and split k
//    8-ways (wave w: k in [w*128, w*128+128), 4 tiles of 32). K/V staged
//    per wave serves TWO q-tiles -> K/V traffic 131 -> 66 MB.
//  - D/E/M loaded as 12 independent float4/int4 plain loads clustered
//    between the K/V DMAs and the vmcnt(0) asm (memory clobber pins them;
//    all 12 dests live until after the wait -> RA cannot chain them).
//    Saves their LDS round-trip; LDS = 16 KB table + 8x8 KB staging.
//  - No k-split partials: 8-wave in-block combine -> direct output.
// Grid (32, 8) = 256 blocks = 1 block/CU, 8 waves/CU (same residency as
// R8). Total VMEM traffic ~164 MB vs R8's 229 MB.
// ---------------------------------------------------------------------------
__global__ __launch_bounds__(512) void attn_kernel(
    const u16* __restrict__ Qb, const u16* __restrict__ Kb, const u16* __restrict__ VTi,
    const float* __restrict__ Dm, const float* __restrict__ Em, const int* __restrict__ Mk,
    const u32* __restrict__ gtab, float* __restrict__ out)
{
    __shared__ __align__(16) u32 sTab[2 * TN];       // 16 KB
    __shared__ __align__(16) char sBuf[69632];       // staging 8x8 KB, then sO
    __shared__ float sM[8][32], sL[8][32];

    const int tid = threadIdx.x;
    {   // stage tables: 1024 uint4 over 512 threads
        const uint4* g4 = (const uint4*)gtab;
        uint4* s4 = (uint4*)sTab;
        s4[tid] = g4[tid];
        s4[tid + 512] = g4[tid + 512];
    }
    __syncthreads();

    const int h    = blockIdx.y;
    const int q0   = blockIdx.x * 32;       // block's 32-row q-panel
    const int wave = tid >> 6;              // 0..7, splits k
    const int lane = tid & 63;
    const int quad = lane >> 4;
    const int l16  = lane & 15;

    const u16* Qh = Qb  + (size_t)h * Sn * Dn;
    const u16* Kh = Kb  + (size_t)h * Sn * Dn;
    const u16* Vh = VTi + (size_t)h * Dn * Sn;
    const float* Dh0 = Dm + (size_t)h * Sn * Sn + (size_t)(q0 + l16) * Sn;
    const float* Eh0 = Em + (size_t)h * Sn * Sn + (size_t)(q0 + l16) * Sn;
    const int*   Mh0 = Mk + (size_t)h * Sn * Sn + (size_t)(q0 + l16) * Sn;
    const float* Dh1 = Dh0 + 16 * Sn;
    const float* Eh1 = Eh0 + 16 * Sn;
    const int*   Mh1 = Mh0 + 16 * Sn;
    const float invhD = (float)TN / RD;
    const float invhE = (float)TN / RE;
    const float scale = 0.08838834764831845f;       // 1/sqrt(2*64)

    // Persistent Q B-fragments for the two 16-row q-tiles (shared by waves)
    const bf16x8 bQ00 = *(const bf16x8*)(Qh + (q0 + l16) * Dn + quad * 8);
    const bf16x8 bQ01 = *(const bf16x8*)(Qh + (q0 + l16) * Dn + 32 + quad * 8);
    const bf16x8 bQ10 = *(const bf16x8*)(Qh + (q0 + 16 + l16) * Dn + quad * 8);
    const bf16x8 bQ11 = *(const bf16x8*)(Qh + (q0 + 16 + l16) * Dn + 32 + quad * 8);

    char* st = sBuf + wave * 8192;          // wave-private K/V staging

    f32x4 OA0 = {0.f,0.f,0.f,0.f}, OA1 = OA0, OA2 = OA0, OA3 = OA0;
    f32x4 OB0 = OA0, OB1 = OA0, OB2 = OA0, OB3 = OA0;
    float mA = -1e30f, lA = 0.f, mB = -1e30f, lB = 0.f;

    for (int t = 0; t < 4; t++) {
        const int k0 = wave * 128 + t * 32;

        // ---- K/V: 8 fire-and-forget DMAs into private LDS ----
        const u16* kr = Kh + (size_t)(k0 + l16) * Dn + quad * 8;
        const u16* vr = Vh + k0 + quad * 8 + (size_t)l16 * Sn;
        stage16(kr,                st);
        stage16(kr + 32,           st + 1024);
        stage16(kr + 16 * Dn,      st + 2048);
        stage16(kr + 16 * Dn + 32, st + 3072);
        stage16(vr,                st + 4096);
        stage16(vr + 16 * Sn,      st + 5120);
        stage16(vr + 32 * Sn,      st + 6144);
        stage16(vr + 48 * Sn,      st + 7168);

        // ---- D/E/M: 12 independent plain loads (cluster before the wait) --
        const float4 DvA0 = *(const float4*)(Dh0 + k0 + quad * 4);
        const float4 DvA1 = *(const float4*)(Dh0 + k0 + 16 + quad * 4);
        const float4 EvA0 = *(const float4*)(Eh0 + k0 + quad * 4);
        const float4 EvA1 = *(const float4*)(Eh0 + k0 + 16 + quad * 4);
        const int4   MvA0 = *(const int4*)(Mh0 + k0 + quad * 4);
        const int4   MvA1 = *(const int4*)(Mh0 + k0 + 16 + quad * 4);
        const float4 DvB0 = *(const float4*)(Dh1 + k0 + quad * 4);
        const float4 DvB1 = *(const float4*)(Dh1 + k0 + 16 + quad * 4);
        const float4 EvB0 = *(const float4*)(Eh1 + k0 + quad * 4);
        const float4 EvB1 = *(const float4*)(Eh1 + k0 + 16 + quad * 4);
        const int4   MvB0 = *(const int4*)(Mh1 + k0 + quad * 4);
        const int4   MvB1 = *(const int4*)(Mh1 + k0 + 16 + quad * 4);

        // one wait per tile covers DMAs + plain loads (both count vmcnt)
        asm volatile("s_waitcnt vmcnt(0)" ::: "memory");

        // identity readback of K/V
        const char* ls = st + lane * 16;
        const bf16x8 aK00 = *(const bf16x8*)(ls);
        const bf16x8 aK01 = *(const bf16x8*)(ls + 1024);
        const bf16x8 aK10 = *(const bf16x8*)(ls + 2048);
        const bf16x8 aK11 = *(const bf16x8*)(ls + 3072);
        const bf16x8 bV0  = *(const bf16x8*)(ls + 4096);
        const bf16x8 bV1  = *(const bf16x8*)(ls + 5120);
        const bf16x8 bV2  = *(const bf16x8*)(ls + 6144);
        const bf16x8 bV3  = *(const bf16x8*)(ls + 7168);

        // pin this tile's LDS reads before next tile's DMA overwrites
        asm volatile("" ::: "memory");

        // ---- QK^T for both q-tiles (K frags shared) ----
        f32x4 sA0 = {0.f,0.f,0.f,0.f}, sA1 = sA0, sB0 = sA0, sB1 = sA0;
        sA0 = __builtin_amdgcn_mfma_f32_16x16x32_bf16(aK00, bQ00, sA0, 0, 0, 0);
        sA0 = __builtin_amdgcn_mfma_f32_16x16x32_bf16(aK01, bQ01, sA0, 0, 0, 0);
        sA1 = __builtin_amdgcn_mfma_f32_16x16x32_bf16(aK10, bQ00, sA1, 0, 0, 0);
        sA1 = __builtin_amdgcn_mfma_f32_16x16x32_bf16(aK11, bQ01, sA1, 0, 0, 0);
        sB0 = __builtin_amdgcn_mfma_f32_16x16x32_bf16(aK00, bQ10, sB0, 0, 0, 0);
        sB0 = __builtin_amdgcn_mfma_f32_16x16x32_bf16(aK01, bQ11, sB0, 0, 0, 0);
        sB1 = __builtin_amdgcn_mfma_f32_16x16x32_bf16(aK10, bQ10, sB1, 0, 0, 0);
        sB1 = __builtin_amdgcn_mfma_f32_16x16x32_bf16(aK11, bQ11, sB1, 0, 0, 0);

        const float dvA0[4] = {DvA0.x, DvA0.y, DvA0.z, DvA0.w};
        const float dvA1[4] = {DvA1.x, DvA1.y, DvA1.z, DvA1.w};
        const float evA0[4] = {EvA0.x, EvA0.y, EvA0.z, EvA0.w};
        const float evA1[4] = {EvA1.x, EvA1.y, EvA1.z, EvA1.w};
        const int   mvA0[4] = {MvA0.x, MvA0.y, MvA0.z, MvA0.w};
        const int   mvA1[4] = {MvA1.x, MvA1.y, MvA1.z, MvA1.w};
        const float dvB0[4] = {DvB0.x, DvB0.y, DvB0.z, DvB0.w};
        const float dvB1[4] = {DvB1.x, DvB1.y, DvB1.z, DvB1.w};
        const float evB0[4] = {EvB0.x, EvB0.y, EvB0.z, EvB0.w};
        const float evB1[4] = {EvB1.x, EvB1.y, EvB1.z, EvB1.w};
        const int   mvB0[4] = {MvB0.x, MvB0.y, MvB0.z, MvB0.w};
        const int   mvB1[4] = {MvB1.x, MvB1.y, MvB1.z, MvB1.w};

        float scA0[4], scA1[4], scB0[4], scB1[4];
#pragma unroll
        for (int r = 0; r < 4; r++) {
            float a0 = sA0[r] * scale + lerp_tab(sTab, dvA0[r], invhD)
                                      + lerp_tab(sTab + TN, evA0[r], invhE);
            a0 = fminf(fmaxf(a0, -80.f), 80.f);
            scA0[r] = (mvA0[r] == 0) ? -1e9f : a0;
            float a1 = sA1[r] * scale + lerp_tab(sTab, dvA1[r], invhD)
                                      + lerp_tab(sTab + TN, evA1[r], invhE);
            a1 = fminf(fmaxf(a1, -80.f), 80.f);
            scA1[r] = (mvA1[r] == 0) ? -1e9f : a1;
            float b0 = sB0[r] * scale + lerp_tab(sTab, dvB0[r], invhD)
                                      + lerp_tab(sTab + TN, evB0[r], invhE);
            b0 = fminf(fmaxf(b0, -80.f), 80.f);
            scB0[r] = (mvB0[r] == 0) ? -1e9f : b0;
            float b1 = sB1[r] * scale + lerp_tab(sTab, dvB1[r], invhD)
                                      + lerp_tab(sTab + TN, evB1[r], invhE);
            b1 = fminf(fmaxf(b1, -80.f), 80.f);
            scB1[r] = (mvB1[r] == 0) ? -1e9f : b1;
        }

        // ---- online softmax, q-tile A ----
        {
            float mloc = fmaxf(fmaxf(fmaxf(scA0[0], scA0[1]), fmaxf(scA0[2], scA0[3])),
                               fmaxf(fmaxf(scA1[0], scA1[1]), fmaxf(scA1[2], scA1[3])));
            mloc = fmaxf(mloc, __shfl_xor(mloc, 16, 64));
            mloc = fmaxf(mloc, __shfl_xor(mloc, 32, 64));
            const float mn = fmaxf(mA, mloc);
            const float al = __expf(mA - mn);
            mA = mn;
            float p0[4], p1[4], ll = 0.f;
#pragma unroll
            for (int r = 0; r < 4; r++) {
                p0[r] = __expf(scA0[r] - mn);
                p1[r] = __expf(scA1[r] - mn);
                ll += p0[r] + p1[r];
            }
            ll += __shfl_xor(ll, 16, 64);
            ll += __shfl_xor(ll, 32, 64);
            lA = lA * al + ll;
            bf16x8 aP;
#pragma unroll
            for (int r = 0; r < 4; r++) {
                aP[r]     = (short)f2bf(p0[r]);
                aP[4 + r] = (short)f2bf(p1[r]);
            }
            const float a0 = __shfl(al, quad * 4 + 0, 64);
            const float a1 = __shfl(al, quad * 4 + 1, 64);
            const float a2 = __shfl(al, quad * 4 + 2, 64);
            const float a3 = __shfl(al, quad * 4 + 3, 64);
            OA0[0] *= a0; OA0[1] *= a1; OA0[2] *= a2; OA0[3] *= a3;
            OA1[0] *= a0; OA1[1] *= a1; OA1[2] *= a2; OA1[3] *= a3;
            OA2[0] *= a0; OA2[1] *= a1; OA2[2] *= a2; OA2[3] *= a3;
            OA3[0] *= a0; OA3[1] *= a1; OA3[2] *= a2; OA3[3] *= a3;
            OA0 = __builtin_amdgcn_mfma_f32_16x16x32_bf16(aP, bV0, OA0, 0, 0, 0);
            OA1 = __builtin_amdgcn_mfma_f32_16x16x32_bf16(aP, bV1, OA1, 0, 0, 0);
            OA2 = __builtin_amdgcn_mfma_f32_16x16x32_bf16(aP, bV2, OA2, 0, 0, 0);
            OA3 = __builtin_amdgcn_mfma_f32_16x16x32_bf16(aP, bV3, OA3, 0, 0, 0);
        }
        // ---- online softmax, q-tile B ----
        {
            float mloc = fmaxf(fmaxf(fmaxf(scB0[0], scB0[1]), fmaxf(scB0[2], scB0[3])),
                               fmaxf(fmaxf(scB1[0], scB1[1]), fmaxf(scB1[2], scB1[3])));
            mloc = fmaxf(mloc, __shfl_xor(mloc, 16, 64));
            mloc = fmaxf(mloc, __shfl_xor(mloc, 32, 64));
            const float mn = fmaxf(mB, mloc);
            const float al = __expf(mB - mn);
            mB = mn;
            float p0[4], p1[4], ll = 0.f;
#pragma unroll
            for (int r = 0; r < 4; r++) {
                p0[r] = __expf(scB0[r] - mn);
                p1[r] = __expf(scB1[r] - mn);
                ll += p0[r] + p1[r];
            }
            ll += __shfl_xor(ll, 16, 64);
            ll += __shfl_xor(ll, 32, 64);
            lB = lB * al + ll;
            bf16x8 aP;
#pragma unroll
            for (int r = 0; r < 4; r++) {
                aP[r]     = (short)f2bf(p0[r]);
                aP[4 + r] = (short)f2bf(p1[r]);
            }
            const float a0 = __shfl(al, quad * 4 + 0, 64);
            const float a1 = __shfl(al, quad * 4 + 1, 64);
            const float a2 = __shfl(al, quad * 4 + 2, 64);
            const float a3 = __shfl(al, quad * 4 + 3, 64);
            OB0[0] *= a0; OB0[1] *= a1; OB0[2] *= a2; OB0[3] *= a3;
            OB1[0] *= a0; OB1[1] *= a1; OB1[2] *= a2; OB1[3] *= a3;
            OB2[0] *= a0; OB2[1] *= a1; OB2[2] *= a2; OB2[3] *= a3;
            OB3[0] *= a0; OB3[1] *= a1; OB3[2] *= a2; OB3[3] *= a3;
            OB0 = __builtin_amdgcn_mfma_f32_16x16x32_bf16(aP, bV0, OB0, 0, 0, 0);
            OB1 = __builtin_amdgcn_mfma_f32_16x16x32_bf16(aP, bV1, OB1, 0, 0, 0);
            OB2 = __builtin_amdgcn_mfma_f32_16x16x32_bf16(aP, bV2, OB2, 0, 0, 0);
            OB3 = __builtin_amdgcn_mfma_f32_16x16x32_bf16(aP, bV3, OB3, 0, 0, 0);
        }
    }

    // all waves done with staging before sO overlays it
    __syncthreads();

    float (*sO)[32][68] = (float (*)[32][68])sBuf;   // 8*32*68*4 = 69.6 KB
    if (lane < 16) {
        sM[wave][lane]      = mA;
        sL[wave][lane]      = lA;
        sM[wave][16 + lane] = mB;
        sL[wave][16 + lane] = lB;
    }
#pragma unroll
    for (int r = 0; r < 4; r++) {
        const int rw = quad * 4 + r;
        sO[wave][rw][ 0 + l16] = OA0[r];
        sO[wave][rw][16 + l16] = OA1[r];
        sO[wave][rw][32 + l16] = OA2[r];
        sO[wave][rw][48 + l16] = OA3[r];
        sO[wave][16 + rw][ 0 + l16] = OB0[r];
        sO[wave][16 + rw][16 + l16] = OB1[r];
        sO[wave][16 + rw][32 + l16] = OB2[r];
        sO[wave][16 + rw][48 + l16] = OB3[r];
    }
    __syncthreads();

    // 512 threads: row = tid>>4 (0..31), cols (tid&15)*4 + [0,4)
    const int row = tid >> 4;
    const int c4  = (tid & 15) * 4;
    float mg = sM[0][row];
#pragma unroll
    for (int w = 1; w < 8; w++) mg = fmaxf(mg, sM[w][row]);
    float fac[8], lg = 0.f;
#pragma unroll
    for (int w = 0; w < 8; w++) {
        fac[w] = __expf(sM[w][row] - mg);
        lg += sL[w][row] * fac[w];
    }
    const float inv = 1.0f / lg;

    float acc[4];
#pragma unroll
    for (int c = 0; c < 4; c++) {
        acc[c] = 0.f;
#pragma unroll
        for (int w = 0; w < 8; w++) acc[c] += sO[w][row][c4 + c] * fac[w];
        acc[c] *= inv;
    }
    float4 ov = {acc[0], acc[1], acc[2], acc[3]};
    *(float4*)(out + ((size_t)(h * Sn + q0 + row)) * Dn + c4) = ov;
}

// ---------------------------------------------------------------------------
extern "C" void kernel_launch(void* const* d_in, const int* in_sizes, int n_in,
                              void* d_out, int out_size, void* d_ws, size_t ws_size,
                              hipStream_t stream) {
    const float* Q    = (const float*)d_in[0];
    const float* K    = (const float*)d_in[1];
    const float* V    = (const float*)d_in[2];
    const float* Dm   = (const float*)d_in[3];
    const float* Em   = (const float*)d_in[4];
    const int*   Mask = (const int*)d_in[5];
    const float* muD  = (const float*)d_in[6];
    const float* sgD  = (const float*)d_in[7];
    const float* bD   = (const float*)d_in[8];
    const float* muE  = (const float*)d_in[9];
    const float* sgE  = (const float*)d_in[10];
    const float* bE   = (const float*)d_in[11];
    const float* W1   = (const float*)d_in[12];
    const float* b1   = (const float*)d_in[13];
    const float* W2   = (const float*)d_in[14];
    const float* b2   = (const float*)d_in[15];

    // ws layout: tab 16 KB | Qb 1 MB | Kb 1 MB | VTi 1 MB  (~3.1 MB total)
    u32* tab = (u32*)d_ws;
    u16* Qb  = (u16*)((char*)d_ws + 2 * TN * 4);
    u16* Kb  = Qb + (size_t)Hn * Sn * Dn;
    u16* VTi = Kb + (size_t)Hn * Sn * Dn;

    const int prep_threads = 2 * TN + QK4 + VTN;           // 790528
    prep_kernel<<<prep_threads / 256, 256, 0, stream>>>(
        Q, K, V, muD, sgD, bD, muE, sgE, bE, W1, b1, W2, b2,
        tab, Qb, Kb, VTi);

    dim3 grid(Sn / 32, Hn);
    attn_kernel<<<grid, 512, 0, stream>>>(Qb, Kb, VTi, Dm, Em, Mask, tab,
                                          (float*)d_out);
}